// Round 9
// baseline (5000.031 us; speedup 1.0000x reference)
//
#include <hip/hip_runtime.h>
#include <cstdint>
#include <cstddef>

#define NEGV -1.0e9f
#define FT 64             // forward tile: 64 rows (1 wave, 1 row/lane) x 64 cols

// Branchless logaddexp, bit-identical to the verified branch form.
__device__ __forceinline__ float lse_f(float a, float b) {
    float d = a - b;
    float m = fmaxf(a, b);
    return m + log1pf(expf(-fabsf(d)));
}
__device__ __forceinline__ float cellfwd(float th, float vu, float vdg, float vl, float A) {
    float inner = lse_f(vu + A, vdg);
    float outer = lse_f(inner, vl + A);
    return th + outer;
}

// Packed anti-diagonal geometry for the bundle buffer.
// Cells (rb, cj): rb in [0,64), cj in [0,1024); d = rb + cj in [0,1087).
// start(d) in cell units (1 cell = 48 floats), L = diagonal length, tlo = first rb.
__device__ __forceinline__ void diag_geo(int d, int& st, int& L, int& tlo) {
    if (d < 64)        { st = (d * (d + 1)) >> 1;       L = d + 1;      tlo = 0; }
    else if (d < 1024) { st = 2080 + ((d - 64) << 6);   L = 64;         tlo = 0; }
    else               { int u = d - 1024;
                         st = 63520 + (u << 6) - ((u * (u + 1)) >> 1);
                         L = 63 - u;                    tlo = u + 1; }
}
// float index within a diagonal: addr = st*48 + (f>>2)*4*L + p*4 + (f&3)
// where p = rb - tlo, f = 3*q + comp (comp: 0=wu, 1=wd, 2=wl).

// ---------------------------------------------------------------------------
// K1: T = emb @ W + b   (f64 accumulate), T: [22][512]
// ---------------------------------------------------------------------------
__global__ void k_embed(const float* __restrict__ emb, const float* __restrict__ W,
                        const float* __restrict__ b, double* __restrict__ T) {
    int idx = blockIdx.x * blockDim.x + threadIdx.x;
    if (idx >= 22 * 512) return;
    int a = idx >> 9, d = idx & 511;
    double acc = (double)b[d];
    const float* er = emb + a * 512;
    for (int k = 0; k < 512; ++k) acc += (double)er[k] * (double)W[k * 512 + d];
    T[idx] = acc;
}

// ---------------------------------------------------------------------------
// K2: G = T @ T^T (22x22), u1/u2 = T @ Wg halves, A[b] via index sums
// ---------------------------------------------------------------------------
__global__ void k_gau(const double* __restrict__ T, const int* __restrict__ x,
                      const int* __restrict__ y, const float* __restrict__ Wg,
                      const float* __restrict__ bg,
                      double* __restrict__ G, double* __restrict__ Aout) {
    __shared__ double u1s[22], u2s[22];
    int t = threadIdx.x;
    if (t < 484) {
        int a = t / 22, c = t % 22;
        const double* ra = T + a * 512;
        const double* rc = T + c * 512;
        double acc = 0.0;
        for (int d = 0; d < 512; ++d) acc += ra[d] * rc[d];
        G[t] = acc;
    }
    if (t < 22) {
        double acc = 0.0;
        const double* ra = T + t * 512;
        for (int d = 0; d < 512; ++d) acc += ra[d] * (double)Wg[d];
        u1s[t] = acc;
    } else if (t >= 64 && t < 86) {
        int a = t - 64;
        double acc = 0.0;
        const double* ra = T + a * 512;
        for (int d = 0; d < 512; ++d) acc += ra[d] * (double)Wg[512 + d];
        u2s[a] = acc;
    }
    __syncthreads();
    int w = t >> 6, lane = t & 63;
    const int* xb = x + w * 1024;
    const int* yb = y + w * 1024;
    double s = 0.0;
    for (int i = lane; i < 1024; i += 64) s += u1s[xb[i]] + u2s[yb[i]];
    for (int off = 32; off > 0; off >>= 1) s += __shfl_down(s, off);
    if (lane == 0) Aout[w] = s * (1.0 / 1024.0) + (double)bg[0];
}

// ---------------------------------------------------------------------------
// K3a: init V boundary (row 0 / col 0) + zero the tile flags.
// ---------------------------------------------------------------------------
__global__ void k_vinit(float* __restrict__ Vbuf, int* __restrict__ flags) {
    int b = blockIdx.x, t = threadIdx.x;
    float* Vb = Vbuf + (size_t)b * (1025 * 1025);
    Vb[t] = (t == 0) ? 0.0f : NEGV;                 // V[0][t]
    if (t == 0) Vb[1024] = NEGV;                    // V[0][1024]
    Vb[(size_t)(t + 1) * 1025] = NEGV;              // V[t+1][0]
    if (b < 2) flags[(b << 10) + t] = 0;            // 2048 flags
}

// ---------------------------------------------------------------------------
// K3b: persistent flag-based forward wavefront. 2048 blocks (1 wave each),
//      one per (batch, 64x64 tile). Block waits (device-scope acquire spin)
//      for its top and left tiles, computes (per-cell ops verbatim from the
//      verified kernel), fences, release-stores its flag.
//      bid mapping: bid&7 = batch (XCD-locality heuristic only).
// ---------------------------------------------------------------------------
__global__ __launch_bounds__(64) void k_fwdp(const int* __restrict__ x,
                                             const int* __restrict__ y,
                                             const double* __restrict__ G,
                                             const double* __restrict__ Aarr,
                                             float* __restrict__ Vbuf,
                                             int* __restrict__ flags) {
    __shared__ float Gs[484];
    __shared__ float topv[FT + 1], leftv[FT + 1];
    __shared__ int ys_s[FT];

    const int bid = blockIdx.x;
    const int b = bid & 7;
    const int tile = bid >> 3;
    const int r = tile >> 4;
    const int c = tile & 15;
    const int t = threadIdx.x;
    const int r0 = FT * r, c0 = FT * c;
    float* Vb = Vbuf + (size_t)b * (1025 * 1025);

    // dep-independent loads first (overlap with the spin)
    for (int q = t; q < 484; q += 64) Gs[q] = (float)G[q];
    ys_s[t] = y[(b << 10) + c0 + t];
    const int xs = x[(b << 10) + r0 + t];
    const float A = (float)Aarr[b];

    int* fbase = flags + (b << 8);
    if (r > 0) {
        int* f = fbase + ((r - 1) << 4) + c;
        while (__hip_atomic_load(f, __ATOMIC_ACQUIRE, __HIP_MEMORY_SCOPE_AGENT) == 0)
            __builtin_amdgcn_s_sleep(2);
    }
    if (c > 0) {
        int* f = fbase + (r << 4) + (c - 1);
        while (__hip_atomic_load(f, __ATOMIC_ACQUIRE, __HIP_MEMORY_SCOPE_AGENT) == 0)
            __builtin_amdgcn_s_sleep(2);
    }

    // halo loads AFTER acquire
    topv[t]  = Vb[(size_t)r0 * 1025 + c0 + t];
    leftv[t] = Vb[(size_t)(r0 + t) * 1025 + c0];
    if (t == 0) {
        topv[FT]  = Vb[(size_t)r0 * 1025 + c0 + FT];
        leftv[FT] = Vb[(size_t)(r0 + FT) * 1025 + c0];
    }
    __syncthreads();

    const float* Grow = Gs + xs * 22;
    float* vst = Vb + (size_t)(r0 + 1 + t) * 1025 + (c0 + 1);

    float vp = 0.f, vdgc = 0.f;
    for (int s = 0; s < FT + 63; ++s) {
        float ush = __shfl_up(vp, 1);     // lane t-1's v at col lj
        const int lj = s - t;
        if (lj >= 0 && lj < FT) {
            float vu  = (t == 0) ? topv[lj + 1] : ush;
            float vdg = (lj == 0) ? leftv[t] : vdgc;
            float vl  = (lj == 0) ? leftv[t + 1] : vp;
            float v = cellfwd(Grow[ys_s[lj]], vu, vdg, vl, A);
            vst[lj] = v;
            vp = v; vdgc = vu;
        }
    }

    __threadfence();
    if (t == 0)
        __hip_atomic_store(fbase + (r << 4) + c, 1,
                           __ATOMIC_RELEASE, __HIP_MEMORY_SCOPE_AGENT);
}

// ---------------------------------------------------------------------------
// K4: weight kernel — recompute each cell's softmax weights (bit-identical
//     inputs from stored V), scatter into the packed-diagonal bundle layout.
//     Consumer cell (I,J): rb=(I-1)>>4, q=(I-1)&15, cj=J-1, lane floats
//     f=3q+{0,1,2} = {wu(I+1,J), wd(I+1,J+1), wl(I,J+1)}.
// ---------------------------------------------------------------------------
__global__ __launch_bounds__(256) void k_wb(const double* __restrict__ Aarr,
                                            const float* __restrict__ Vbuf,
                                            float* __restrict__ bw) {
    int idx = blockIdx.x * 256 + threadIdx.x;
    int b = idx >> 20;
    int cell = idx & 1048575;
    int i = (cell >> 10) + 1;        // 1..1024
    int j = (cell & 1023) + 1;       // 1..1024
    const float* Vb = Vbuf + (size_t)b * (1025 * 1025);
    float vu  = Vb[(size_t)(i - 1) * 1025 + j];
    float vdg = Vb[(size_t)(i - 1) * 1025 + (j - 1)];
    float vl  = Vb[(size_t)i * 1025 + (j - 1)];
    float A = (float)Aarr[b];
    float t1 = vu + A;
    float t2 = vl + A;
    float di = t1 - vdg;
    float inner = (di > 0.f) ? (t1  + log1pf(expf(-di)))
                             : (vdg + log1pf(expf(di)));
    float dw = inner - t2;
    float outer = (dw > 0.f) ? (inner + log1pf(expf(-dw)))
                             : (t2    + log1pf(expf(dw)));
    float go1 = expf(inner - outer);
    float wlW = expf(t2 - outer);
    float wuW = go1 * expf(t1 - inner);
    float wdW = go1 * expf(vdg - inner);
    float* bbp = bw + (size_t)b * 3145728;

    // wu -> consumer (i-1, j)
    if (i >= 2) {
        int rb = (i - 2) >> 4, q = (i - 2) & 15, cj = j - 1;
        int st, L, tlo; diag_geo(rb + cj, st, L, tlo);
        int f = 3 * q;
        bbp[(size_t)st * 48 + (size_t)(f >> 2) * 4 * L + ((rb - tlo) << 2) + (f & 3)] = wuW;
    }
    // wd -> consumer (i-1, j-1)
    if (i >= 2 && j >= 2) {
        int rb = (i - 2) >> 4, q = (i - 2) & 15, cj = j - 2;
        int st, L, tlo; diag_geo(rb + cj, st, L, tlo);
        int f = 3 * q + 1;
        bbp[(size_t)st * 48 + (size_t)(f >> 2) * 4 * L + ((rb - tlo) << 2) + (f & 3)] = wdW;
    }
    // wl -> consumer (i, j-1)
    if (j >= 2) {
        int rb = (i - 1) >> 4, q = (i - 1) & 15, cj = j - 2;
        int st, L, tlo; diag_geo(rb + cj, st, L, tlo);
        int f = 3 * q + 2;
        bbp[(size_t)st * 48 + (size_t)(f >> 2) * 4 * L + ((rb - tlo) << 2) + (f & 3)] = wlW;
    }
}

// ---------------------------------------------------------------------------
// K5: single-launch backward, packed-diagonal coalesced bundle reads.
//     One wave per batch; lane t owns rows 16t+1..16t+16; sweeps diagonals
//     d = 1086..0 (lane's column cj = d - t). Per step: 12 coalesced float4
//     loads prefetch the next diagonal; E-chain verbatim from the verified
//     kernel (sequential cell order preserved => bit-identical).
// ---------------------------------------------------------------------------
__global__ __launch_bounds__(64) void k_bwd16(const float* __restrict__ bw,
                                              float* __restrict__ out) {
    const int t = threadIdx.x;
    const int b = blockIdx.x;
    const float* bb = bw + (size_t)b * 3145728;
    float* ob = out + ((size_t)b << 20);
    const int r0 = t << 4;              // (i-1) base = 16t

    float e[16];
    float4 cwv[12], pfv[12];
    #pragma unroll
    for (int q = 0; q < 16; ++q) e[q] = 0.f;

    // preload this lane's first active column (cj=1023): d = t+1023, p = 0
    {
        int st, L, tlo; diag_geo(t + 1023, st, L, tlo);
        const float* base = bb + (size_t)st * 48;
        #pragma unroll
        for (int k = 0; k < 12; ++k)
            cwv[k] = *(const float4*)(base + (size_t)k * 4 * L);
    }

    float sdb = 0.f;
    for (int s = 0; s < 1087; ++s) {
        float dn = __shfl_down(e[0], 1);    // lane t+1's top value at col cj
        const int d = 1086 - s;
        const int cj = d - t;               // this lane's column (j-1)
        if (cj >= 0 && cj < 1024) {
            // prefetch next diagonal (d-1), p = t - tlo(d-1); safe even at cj==0
            {
                int st, L, tlo; diag_geo(d - 1, st, L, tlo);
                const int p = t - tlo;
                const float* base = bb + (size_t)st * 48 + ((size_t)p << 2);
                #pragma unroll
                for (int k = 0; k < 12; ++k)
                    pfv[k] = *(const float4*)(base + (size_t)k * 4 * L);
            }
            const float* F = (const float*)cwv;   // 48 floats, static indexing only

            // q = 15 (bottom row of the lane's strip)
            float old_b = e[15];
            float eu = (t == 63) ? 0.f : dn;        // E[i+1][j]
            float ed = (t == 63) ? 0.f : sdb;       // E[i+1][j+1]
            float v = eu * F[45] + ed * F[46] + old_b * F[47];
            if (t == 63 && cj == 1023) v = 1.0f;    // seed E[1024][1024] = 1
            e[15] = v;
            float new_b = v;
            #pragma unroll
            for (int q = 14; q >= 0; --q) {
                float oq = e[q];
                v = new_b * F[3 * q] + old_b * F[3 * q + 1] + oq * F[3 * q + 2];
                e[q] = v;
                new_b = v; old_b = oq;
            }
            // store 16 consecutive rows at column cj (out[j-1][i-1])
            #pragma unroll
            for (int k = 0; k < 4; ++k)
                *(float4*)&ob[(size_t)cj * 1024 + r0 + 4 * k] =
                    make_float4(e[4*k], e[4*k+1], e[4*k+2], e[4*k+3]);
            // rotate prefetch
            #pragma unroll
            for (int k = 0; k < 12; ++k) cwv[k] = pfv[k];
        }
        sdb = dn;       // lane t+1's value at col cj+1 for next step
    }
}

// ---------------------------------------------------------------------------
// Fallback: round-2 monolithic forward+backward (used only if ws too small).
// ---------------------------------------------------------------------------
template <bool FAITHFUL>
__global__ __launch_bounds__(1024) void k_dp(const int* __restrict__ x,
                                             const int* __restrict__ y,
                                             const double* __restrict__ G,
                                             const double* __restrict__ Aarr,
                                             float2* __restrict__ wbuf,
                                             float* __restrict__ wdbuf,
                                             float* __restrict__ out) {
    __shared__ float Gs[484];
    __shared__ int xs[1024], ys[1024];
    __shared__ float D[3][1025];
    __shared__ float E[3][1026];

    const int b = blockIdx.x;
    const int t = threadIdx.x;
    const int i = t + 1;

    if (t < 484) Gs[t] = (float)G[t];
    xs[t] = x[(b << 10) + t];
    ys[t] = y[(b << 10) + t];
    D[0][t + 1] = NEGV;
    D[1][t + 1] = NEGV;
    E[0][t] = 0.f; E[1][t] = 0.f; E[2][t] = 0.f;
    if (t == 0) {
        D[0][0] = 0.0f;
        D[1][0] = NEGV;
        E[0][1024] = 0.f; E[0][1025] = 0.f;
        E[1][1024] = 0.f; E[1][1025] = 0.f;
        E[2][1024] = 0.f; E[2][1025] = 0.f;
    }
    __syncthreads();

    const float A = (float)Aarr[b];
    const float* Grow = Gs + xs[t] * 22;
    float2* wb = wbuf + ((size_t)b << 20);
    float*  wdb = wdbuf + ((size_t)b << 20);

    for (int k = 2; k <= 2048; ++k) {
        const int cur = k % 3, p1 = (k + 2) % 3, p2 = (k + 1) % 3;
        const int j = k - i;
        if (j >= 1 && j <= 1024) {
            float vu  = D[p1][i - 1];
            float vdg = D[p2][i - 1];
            float vl  = D[p1][i];
            float t1 = vu + A;
            float t2 = vl + A;
            float di = t1 - vdg;
            float inner = (di > 0.f) ? (t1  + log1pf(expf(-di)))
                                     : (vdg + log1pf(expf(di)));
            float dw = inner - t2;
            float outer = (dw > 0.f) ? (inner + log1pf(expf(-dw)))
                                     : (t2    + log1pf(expf(dw)));
            D[cur][i] = Grow[ys[j - 1]] + outer;
            float go1 = expf(inner - outer);
            float wlW = expf(t2 - outer);
            float wuW = go1 * expf(t1 - inner);
            size_t ci = ((size_t)t << 10) + (j - 1);
            wb[ci] = make_float2(wuW, wlW);
            if (FAITHFUL) wdb[ci] = go1 * expf(vdg - inner);
        }
        if (t == 0) D[cur][0] = NEGV;
        if (i == k && k <= 1024) D[cur][k] = NEGV;
        __syncthreads();
    }

    __syncthreads();

    float* ob = out + ((size_t)b << 20);

    for (int k = 2048; k >= 2; --k) {
        const int cur = k % 3, n1 = (k + 1) % 3, n2 = (k + 2) % 3;
        const int j = k - i;
        if (j >= 1 && j <= 1024) {
            float e;
            if (k == 2048) {
                e = 1.0f;
            } else {
                float Eu = E[n1][i + 1];
                float Ed = E[n2][i + 1];
                float El = E[n1][i];
                int iw = (i < 1024) ? i : 1023;
                int jw = (j < 1024) ? j : 1023;
                float2 w_up = wb[((size_t)iw << 10) + (j - 1)];
                float2 w_lf = wb[((size_t)(i - 1) << 10) + jw];
                float w_dd;
                if (FAITHFUL) {
                    w_dd = wdb[((size_t)iw << 10) + jw];
                } else {
                    float2 w_dg = wb[((size_t)iw << 10) + jw];
                    w_dd = 1.0f - w_dg.x - w_dg.y;
                }
                e = Eu * w_up.x + Ed * w_dd + El * w_lf.y;
            }
            E[cur][i] = e;
            ob[((size_t)(j - 1) << 10) + (i - 1)] = e;
        } else {
            E[cur][i] = 0.f;
        }
        __syncthreads();
    }
}

// ---------------------------------------------------------------------------
extern "C" void kernel_launch(void* const* d_in, const int* in_sizes, int n_in,
                              void* d_out, int out_size, void* d_ws, size_t ws_size,
                              hipStream_t stream) {
    const int*   x   = (const int*)d_in[0];
    const int*   y   = (const int*)d_in[1];
    const float* emb = (const float*)d_in[2];
    const float* W   = (const float*)d_in[3];
    const float* b   = (const float*)d_in[4];
    const float* Wg  = (const float*)d_in[5];
    const float* bg  = (const float*)d_in[6];
    float* out = (float*)d_out;

    char* ws = (char*)d_ws;
    double* T    = (double*)(ws + 0);                       // 90112 B
    double* G    = (double*)(ws + 90112);                   // 3872 B
    double* Aarr = (double*)(ws + 94336);                   // 64 B
    float*  bund = (float*)(ws + 131072);                   // 96 MiB (packed diagonals)
    float2* wbuf = (float2*)(ws + 131072);                  // (fallback layout)
    float*  wdbuf = (float*)(ws + 131072 + ((size_t)64 << 20));
    float*  Vbuf = (float*)(ws + 131072 + ((size_t)96 << 20));   // 33.6 MB
    int*    flags = (int*)(ws + 131072 + ((size_t)96 << 20) + (size_t)8 * 1025 * 1025 * 4);

    k_embed<<<44, 256, 0, stream>>>(emb, W, b, T);
    k_gau<<<1, 512, 0, stream>>>(T, x, y, Wg, bg, G, Aarr);

    const size_t need_old = 131072 + ((size_t)96 << 20);
    const size_t need_new = need_old + (size_t)8 * 1025 * 1025 * 4 + 8192;

    if (ws_size >= need_new) {
        k_vinit<<<8, 1024, 0, stream>>>(Vbuf, flags);
        k_fwdp<<<2048, 64, 0, stream>>>(x, y, G, Aarr, Vbuf, flags);
        k_wb<<<8 * 1024 * 1024 / 256, 256, 0, stream>>>(Aarr, Vbuf, bund);
        k_bwd16<<<8, 64, 0, stream>>>(bund, out);
    } else if (ws_size >= need_old) {
        k_dp<true><<<8, 1024, 0, stream>>>(x, y, G, Aarr, wbuf, wdbuf, out);
    } else {
        k_dp<false><<<8, 1024, 0, stream>>>(x, y, G, Aarr, wbuf, wdbuf, out);
    }
}

// Round 10
// 3159.424 us; speedup vs baseline: 1.5826x; 1.5826x over previous
//
#include <hip/hip_runtime.h>
#include <cstdint>
#include <cstddef>

#define NEGV -1.0e9f
#define WAVES 16

// Branchless logaddexp, bit-identical to the verified branch form.
__device__ __forceinline__ float lse_f(float a, float b) {
    float d = a - b;
    float m = fmaxf(a, b);
    return m + log1pf(expf(-fabsf(d)));
}
__device__ __forceinline__ float cellfwd(float th, float vu, float vdg, float vl, float A) {
    float inner = lse_f(vu + A, vdg);
    float outer = lse_f(inner, vl + A);
    return th + outer;
}

// Packed anti-diagonal geometry for the bundle buffer.
// Cells (rb, cj): rb in [0,64), cj in [0,1024); d = rb + cj in [0,1087).
__device__ __forceinline__ void diag_geo(int d, int& st, int& L, int& tlo) {
    if (d < 64)        { st = (d * (d + 1)) >> 1;       L = d + 1;      tlo = 0; }
    else if (d < 1024) { st = 2080 + ((d - 64) << 6);   L = 64;         tlo = 0; }
    else               { int u = d - 1024;
                         st = 63520 + (u << 6) - ((u * (u + 1)) >> 1);
                         L = 63 - u;                    tlo = u + 1; }
}

// ---------------------------------------------------------------------------
// K1: T = emb @ W + b   (f64 accumulate), T: [22][512]
// ---------------------------------------------------------------------------
__global__ void k_embed(const float* __restrict__ emb, const float* __restrict__ W,
                        const float* __restrict__ b, double* __restrict__ T) {
    int idx = blockIdx.x * blockDim.x + threadIdx.x;
    if (idx >= 22 * 512) return;
    int a = idx >> 9, d = idx & 511;
    double acc = (double)b[d];
    const float* er = emb + a * 512;
    for (int k = 0; k < 512; ++k) acc += (double)er[k] * (double)W[k * 512 + d];
    T[idx] = acc;
}

// ---------------------------------------------------------------------------
// K2: G = T @ T^T (22x22), u1/u2 = T @ Wg halves, A[b] via index sums
// ---------------------------------------------------------------------------
__global__ void k_gau(const double* __restrict__ T, const int* __restrict__ x,
                      const int* __restrict__ y, const float* __restrict__ Wg,
                      const float* __restrict__ bg,
                      double* __restrict__ G, double* __restrict__ Aout) {
    __shared__ double u1s[22], u2s[22];
    int t = threadIdx.x;
    if (t < 484) {
        int a = t / 22, c = t % 22;
        const double* ra = T + a * 512;
        const double* rc = T + c * 512;
        double acc = 0.0;
        for (int d = 0; d < 512; ++d) acc += ra[d] * rc[d];
        G[t] = acc;
    }
    if (t < 22) {
        double acc = 0.0;
        const double* ra = T + t * 512;
        for (int d = 0; d < 512; ++d) acc += ra[d] * (double)Wg[d];
        u1s[t] = acc;
    } else if (t >= 64 && t < 86) {
        int a = t - 64;
        double acc = 0.0;
        const double* ra = T + a * 512;
        for (int d = 0; d < 512; ++d) acc += ra[d] * (double)Wg[512 + d];
        u2s[a] = acc;
    }
    __syncthreads();
    int w = t >> 6, lane = t & 63;
    const int* xb = x + w * 1024;
    const int* yb = y + w * 1024;
    double s = 0.0;
    for (int i = lane; i < 1024; i += 64) s += u1s[xb[i]] + u2s[yb[i]];
    for (int off = 32; off > 0; off >>= 1) s += __shfl_down(s, off);
    if (lane == 0) Aout[w] = s * (1.0 / 1024.0) + (double)bg[0];
}

// ---------------------------------------------------------------------------
// K3a: init V boundary (row 0 / col 0). Vbuf[b][i][j], stride 1025.
// ---------------------------------------------------------------------------
__global__ void k_vinit(float* __restrict__ Vbuf) {
    int b = blockIdx.x, t = threadIdx.x;
    float* Vb = Vbuf + (size_t)b * (1025 * 1025);
    Vb[t] = (t == 0) ? 0.0f : NEGV;                 // V[0][t]
    if (t == 0) Vb[1024] = NEGV;                    // V[0][1024]
    Vb[(size_t)(t + 1) * 1025] = NEGV;              // V[t+1][0]
}

// ---------------------------------------------------------------------------
// K3b: banded forward, ONE block per batch (1024 thr = 16 waves). Wave w owns
//      rows 64w+1..64w+64 (1 row/lane) and sweeps all 1024 columns in one
//      continuous 1087-step pipeline. Inter-wave handoff of the band's bottom
//      row goes through LDS (topbuf) with a per-wave progress counter
//      (WORKGROUP-scope atomics = ds ops only; release/acquire order is
//      guaranteed by in-order DS execution). Per-cell float ops verbatim from
//      the verified kernels -> bit-identical V.
// ---------------------------------------------------------------------------
__global__ __launch_bounds__(1024) void k_fwdb(const int* __restrict__ x,
                                               const int* __restrict__ y,
                                               const double* __restrict__ G,
                                               const double* __restrict__ Aarr,
                                               float* __restrict__ Vbuf) {
    __shared__ float Gs[484];
    __shared__ int ys_s[1024];
    __shared__ float topbuf[WAVES][1024];   // topbuf[w][c] = V[64w][c+1]
    __shared__ int prog[WAVES];

    const int b = blockIdx.x;
    const int tid = threadIdx.x;
    const int w = tid >> 6;                 // wave = row band
    const int t = tid & 63;                 // lane = row within band
    float* Vb = Vbuf + (size_t)b * (1025 * 1025);

    if (tid < 484) Gs[tid] = (float)G[tid];
    ys_s[tid] = y[(b << 10) + tid];
    if (tid < WAVES) prog[tid] = 0;
    const int xs = x[(b << 10) + tid];      // row - 1 == tid
    __syncthreads();

    const float A = (float)Aarr[b];
    const float* Grow = Gs + xs * 22;
    float* vst = Vb + (size_t)(tid + 1) * 1025 + 1;   // vst[j-1] = V[row][j]

    float vp = NEGV;                                   // V[row][j-1] carry
    float vdgc = (tid == 0) ? 0.0f : NEGV;             // V[row-1][j-1] carry seed

    for (int s = 0; s < 1024 + 63; ++s) {
        // group-sync: wave w needs topbuf[w][s..s+15] before this 16-col group
        if (w > 0 && s < 1024 && (s & 15) == 0) {
            const int target = (s + 16 < 1024) ? s + 16 : 1024;
            while (__hip_atomic_load(&prog[w], __ATOMIC_ACQUIRE,
                                     __HIP_MEMORY_SCOPE_WORKGROUP) < target)
                __builtin_amdgcn_s_sleep(1);
        }
        const float vu_lds = (w > 0) ? topbuf[w][(s < 1024) ? s : 1023] : NEGV;
        const float ush = __shfl_up(vp, 1);   // lane t-1's v at col j
        const int j = s - t + 1;
        if (j >= 1 && j <= 1024) {
            float vu  = (t == 0) ? vu_lds : ush;
            float v = cellfwd(Grow[ys_s[j - 1]], vu, vdgc, vp, A);
            vst[j - 1] = v;                   // global store stays in flight
            if (w < WAVES - 1 && t == 63) {
                topbuf[w + 1][j - 1] = v;     // hand bottom row to next band
                if ((j & 15) == 0)
                    __hip_atomic_store(&prog[w + 1], j, __ATOMIC_RELEASE,
                                       __HIP_MEMORY_SCOPE_WORKGROUP);
            }
            vp = v; vdgc = vu;
        }
    }
}

// ---------------------------------------------------------------------------
// K4: weight kernel — recompute each cell's softmax weights (bit-identical
//     inputs from stored V), scatter into the packed-diagonal bundle layout.
// ---------------------------------------------------------------------------
__global__ __launch_bounds__(256) void k_wb(const double* __restrict__ Aarr,
                                            const float* __restrict__ Vbuf,
                                            float* __restrict__ bw) {
    int idx = blockIdx.x * 256 + threadIdx.x;
    int b = idx >> 20;
    int cell = idx & 1048575;
    int i = (cell >> 10) + 1;        // 1..1024
    int j = (cell & 1023) + 1;       // 1..1024
    const float* Vb = Vbuf + (size_t)b * (1025 * 1025);
    float vu  = Vb[(size_t)(i - 1) * 1025 + j];
    float vdg = Vb[(size_t)(i - 1) * 1025 + (j - 1)];
    float vl  = Vb[(size_t)i * 1025 + (j - 1)];
    float A = (float)Aarr[b];
    float t1 = vu + A;
    float t2 = vl + A;
    float di = t1 - vdg;
    float inner = (di > 0.f) ? (t1  + log1pf(expf(-di)))
                             : (vdg + log1pf(expf(di)));
    float dw = inner - t2;
    float outer = (dw > 0.f) ? (inner + log1pf(expf(-dw)))
                             : (t2    + log1pf(expf(dw)));
    float go1 = expf(inner - outer);
    float wlW = expf(t2 - outer);
    float wuW = go1 * expf(t1 - inner);
    float wdW = go1 * expf(vdg - inner);
    float* bbp = bw + (size_t)b * 3145728;

    if (i >= 2) {        // wu -> consumer (i-1, j)
        int rb = (i - 2) >> 4, q = (i - 2) & 15, cj = j - 1;
        int st, L, tlo; diag_geo(rb + cj, st, L, tlo);
        int f = 3 * q;
        bbp[(size_t)st * 48 + (size_t)(f >> 2) * 4 * L + ((rb - tlo) << 2) + (f & 3)] = wuW;
    }
    if (i >= 2 && j >= 2) {   // wd -> consumer (i-1, j-1)
        int rb = (i - 2) >> 4, q = (i - 2) & 15, cj = j - 2;
        int st, L, tlo; diag_geo(rb + cj, st, L, tlo);
        int f = 3 * q + 1;
        bbp[(size_t)st * 48 + (size_t)(f >> 2) * 4 * L + ((rb - tlo) << 2) + (f & 3)] = wdW;
    }
    if (j >= 2) {        // wl -> consumer (i, j-1)
        int rb = (i - 1) >> 4, q = (i - 1) & 15, cj = j - 2;
        int st, L, tlo; diag_geo(rb + cj, st, L, tlo);
        int f = 3 * q + 2;
        bbp[(size_t)st * 48 + (size_t)(f >> 2) * 4 * L + ((rb - tlo) << 2) + (f & 3)] = wlW;
    }
}

// ---------------------------------------------------------------------------
// K5: single-launch backward, packed-diagonal coalesced bundle reads.
//     (verbatim from the verified round-9 kernel; bit-identical E order)
// ---------------------------------------------------------------------------
__global__ __launch_bounds__(64) void k_bwd16(const float* __restrict__ bw,
                                              float* __restrict__ out) {
    const int t = threadIdx.x;
    const int b = blockIdx.x;
    const float* bb = bw + (size_t)b * 3145728;
    float* ob = out + ((size_t)b << 20);
    const int r0 = t << 4;              // (i-1) base = 16t

    float e[16];
    float4 cwv[12], pfv[12];
    #pragma unroll
    for (int q = 0; q < 16; ++q) e[q] = 0.f;

    {
        int st, L, tlo; diag_geo(t + 1023, st, L, tlo);
        const float* base = bb + (size_t)st * 48;
        #pragma unroll
        for (int k = 0; k < 12; ++k)
            cwv[k] = *(const float4*)(base + (size_t)k * 4 * L);
    }

    float sdb = 0.f;
    for (int s = 0; s < 1087; ++s) {
        float dn = __shfl_down(e[0], 1);    // lane t+1's top value at col cj
        const int d = 1086 - s;
        const int cj = d - t;               // this lane's column (j-1)
        if (cj >= 0 && cj < 1024) {
            {
                int st, L, tlo; diag_geo(d - 1, st, L, tlo);
                const int p = t - tlo;
                const float* base = bb + (size_t)st * 48 + ((size_t)p << 2);
                #pragma unroll
                for (int k = 0; k < 12; ++k)
                    pfv[k] = *(const float4*)(base + (size_t)k * 4 * L);
            }
            const float* F = (const float*)cwv;

            float old_b = e[15];
            float eu = (t == 63) ? 0.f : dn;
            float ed = (t == 63) ? 0.f : sdb;
            float v = eu * F[45] + ed * F[46] + old_b * F[47];
            if (t == 63 && cj == 1023) v = 1.0f;    // seed E[1024][1024] = 1
            e[15] = v;
            float new_b = v;
            #pragma unroll
            for (int q = 14; q >= 0; --q) {
                float oq = e[q];
                v = new_b * F[3 * q] + old_b * F[3 * q + 1] + oq * F[3 * q + 2];
                e[q] = v;
                new_b = v; old_b = oq;
            }
            #pragma unroll
            for (int k = 0; k < 4; ++k)
                *(float4*)&ob[(size_t)cj * 1024 + r0 + 4 * k] =
                    make_float4(e[4*k], e[4*k+1], e[4*k+2], e[4*k+3]);
            #pragma unroll
            for (int k = 0; k < 12; ++k) cwv[k] = pfv[k];
        }
        sdb = dn;
    }
}

// ---------------------------------------------------------------------------
// Fallback: round-2 monolithic forward+backward (used only if ws too small).
// ---------------------------------------------------------------------------
template <bool FAITHFUL>
__global__ __launch_bounds__(1024) void k_dp(const int* __restrict__ x,
                                             const int* __restrict__ y,
                                             const double* __restrict__ G,
                                             const double* __restrict__ Aarr,
                                             float2* __restrict__ wbuf,
                                             float* __restrict__ wdbuf,
                                             float* __restrict__ out) {
    __shared__ float Gs[484];
    __shared__ int xs[1024], ys[1024];
    __shared__ float D[3][1025];
    __shared__ float E[3][1026];

    const int b = blockIdx.x;
    const int t = threadIdx.x;
    const int i = t + 1;

    if (t < 484) Gs[t] = (float)G[t];
    xs[t] = x[(b << 10) + t];
    ys[t] = y[(b << 10) + t];
    D[0][t + 1] = NEGV;
    D[1][t + 1] = NEGV;
    E[0][t] = 0.f; E[1][t] = 0.f; E[2][t] = 0.f;
    if (t == 0) {
        D[0][0] = 0.0f;
        D[1][0] = NEGV;
        E[0][1024] = 0.f; E[0][1025] = 0.f;
        E[1][1024] = 0.f; E[1][1025] = 0.f;
        E[2][1024] = 0.f; E[2][1025] = 0.f;
    }
    __syncthreads();

    const float A = (float)Aarr[b];
    const float* Grow = Gs + xs[t] * 22;
    float2* wb = wbuf + ((size_t)b << 20);
    float*  wdb = wdbuf + ((size_t)b << 20);

    for (int k = 2; k <= 2048; ++k) {
        const int cur = k % 3, p1 = (k + 2) % 3, p2 = (k + 1) % 3;
        const int j = k - i;
        if (j >= 1 && j <= 1024) {
            float vu  = D[p1][i - 1];
            float vdg = D[p2][i - 1];
            float vl  = D[p1][i];
            float t1 = vu + A;
            float t2 = vl + A;
            float di = t1 - vdg;
            float inner = (di > 0.f) ? (t1  + log1pf(expf(-di)))
                                     : (vdg + log1pf(expf(di)));
            float dw = inner - t2;
            float outer = (dw > 0.f) ? (inner + log1pf(expf(-dw)))
                                     : (t2    + log1pf(expf(dw)));
            D[cur][i] = Grow[ys[j - 1]] + outer;
            float go1 = expf(inner - outer);
            float wlW = expf(t2 - outer);
            float wuW = go1 * expf(t1 - inner);
            size_t ci = ((size_t)t << 10) + (j - 1);
            wb[ci] = make_float2(wuW, wlW);
            if (FAITHFUL) wdb[ci] = go1 * expf(vdg - inner);
        }
        if (t == 0) D[cur][0] = NEGV;
        if (i == k && k <= 1024) D[cur][k] = NEGV;
        __syncthreads();
    }

    __syncthreads();

    float* ob = out + ((size_t)b << 20);

    for (int k = 2048; k >= 2; --k) {
        const int cur = k % 3, n1 = (k + 1) % 3, n2 = (k + 2) % 3;
        const int j = k - i;
        if (j >= 1 && j <= 1024) {
            float e;
            if (k == 2048) {
                e = 1.0f;
            } else {
                float Eu = E[n1][i + 1];
                float Ed = E[n2][i + 1];
                float El = E[n1][i];
                int iw = (i < 1024) ? i : 1023;
                int jw = (j < 1024) ? j : 1023;
                float2 w_up = wb[((size_t)iw << 10) + (j - 1)];
                float2 w_lf = wb[((size_t)(i - 1) << 10) + jw];
                float w_dd;
                if (FAITHFUL) {
                    w_dd = wdb[((size_t)iw << 10) + jw];
                } else {
                    float2 w_dg = wb[((size_t)iw << 10) + jw];
                    w_dd = 1.0f - w_dg.x - w_dg.y;
                }
                e = Eu * w_up.x + Ed * w_dd + El * w_lf.y;
            }
            E[cur][i] = e;
            ob[((size_t)(j - 1) << 10) + (i - 1)] = e;
        } else {
            E[cur][i] = 0.f;
        }
        __syncthreads();
    }
}

// ---------------------------------------------------------------------------
extern "C" void kernel_launch(void* const* d_in, const int* in_sizes, int n_in,
                              void* d_out, int out_size, void* d_ws, size_t ws_size,
                              hipStream_t stream) {
    const int*   x   = (const int*)d_in[0];
    const int*   y   = (const int*)d_in[1];
    const float* emb = (const float*)d_in[2];
    const float* W   = (const float*)d_in[3];
    const float* b   = (const float*)d_in[4];
    const float* Wg  = (const float*)d_in[5];
    const float* bg  = (const float*)d_in[6];
    float* out = (float*)d_out;

    char* ws = (char*)d_ws;
    double* T    = (double*)(ws + 0);                       // 90112 B
    double* G    = (double*)(ws + 90112);                   // 3872 B
    double* Aarr = (double*)(ws + 94336);                   // 64 B
    float*  bund = (float*)(ws + 131072);                   // 96 MiB (packed diagonals)
    float2* wbuf = (float2*)(ws + 131072);                  // (fallback layout)
    float*  wdbuf = (float*)(ws + 131072 + ((size_t)64 << 20));
    float*  Vbuf = (float*)(ws + 131072 + ((size_t)96 << 20));   // 33.6 MB

    k_embed<<<44, 256, 0, stream>>>(emb, W, b, T);
    k_gau<<<1, 512, 0, stream>>>(T, x, y, Wg, bg, G, Aarr);

    const size_t need_old = 131072 + ((size_t)96 << 20);
    const size_t need_new = need_old + (size_t)8 * 1025 * 1025 * 4;

    if (ws_size >= need_new) {
        k_vinit<<<8, 1024, 0, stream>>>(Vbuf);
        k_fwdb<<<8, 1024, 0, stream>>>(x, y, G, Aarr, Vbuf);
        k_wb<<<8 * 1024 * 1024 / 256, 256, 0, stream>>>(Aarr, Vbuf, bund);
        k_bwd16<<<8, 64, 0, stream>>>(bund, out);
    } else if (ws_size >= need_old) {
        k_dp<true><<<8, 1024, 0, stream>>>(x, y, G, Aarr, wbuf, wdbuf, out);
    } else {
        k_dp<false><<<8, 1024, 0, stream>>>(x, y, G, Aarr, wbuf, wdbuf, out);
    }
}

// Round 11
// 2602.678 us; speedup vs baseline: 1.9211x; 1.2139x over previous
//
#include <hip/hip_runtime.h>
#include <cstdint>
#include <cstddef>

#define NEGV -1.0e9f
#define NB 4              // row-blocks per batch
#define BW 4              // waves per row-block

// Branchless logaddexp, bit-identical to the verified branch form.
__device__ __forceinline__ float lse_f(float a, float b) {
    float d = a - b;
    float m = fmaxf(a, b);
    return m + log1pf(expf(-fabsf(d)));
}
__device__ __forceinline__ float cellfwd(float th, float vu, float vdg, float vl, float A) {
    float inner = lse_f(vu + A, vdg);
    float outer = lse_f(inner, vl + A);
    return th + outer;
}

// Packed anti-diagonal geometry for the bundle buffer.
__device__ __forceinline__ void diag_geo(int d, int& st, int& L, int& tlo) {
    if (d < 64)        { st = (d * (d + 1)) >> 1;       L = d + 1;      tlo = 0; }
    else if (d < 1024) { st = 2080 + ((d - 64) << 6);   L = 64;         tlo = 0; }
    else               { int u = d - 1024;
                         st = 63520 + (u << 6) - ((u * (u + 1)) >> 1);
                         L = 63 - u;                    tlo = u + 1; }
}

// ---------------------------------------------------------------------------
// K1: T = emb @ W + b   (f64 accumulate), T: [22][512]
// ---------------------------------------------------------------------------
__global__ void k_embed(const float* __restrict__ emb, const float* __restrict__ W,
                        const float* __restrict__ b, double* __restrict__ T) {
    int idx = blockIdx.x * blockDim.x + threadIdx.x;
    if (idx >= 22 * 512) return;
    int a = idx >> 9, d = idx & 511;
    double acc = (double)b[d];
    const float* er = emb + a * 512;
    for (int k = 0; k < 512; ++k) acc += (double)er[k] * (double)W[k * 512 + d];
    T[idx] = acc;
}

// ---------------------------------------------------------------------------
// K2: G = T @ T^T (22x22), u1/u2 = T @ Wg halves, A[b] via index sums
// ---------------------------------------------------------------------------
__global__ void k_gau(const double* __restrict__ T, const int* __restrict__ x,
                      const int* __restrict__ y, const float* __restrict__ Wg,
                      const float* __restrict__ bg,
                      double* __restrict__ G, double* __restrict__ Aout) {
    __shared__ double u1s[22], u2s[22];
    int t = threadIdx.x;
    if (t < 484) {
        int a = t / 22, c = t % 22;
        const double* ra = T + a * 512;
        const double* rc = T + c * 512;
        double acc = 0.0;
        for (int d = 0; d < 512; ++d) acc += ra[d] * rc[d];
        G[t] = acc;
    }
    if (t < 22) {
        double acc = 0.0;
        const double* ra = T + t * 512;
        for (int d = 0; d < 512; ++d) acc += ra[d] * (double)Wg[d];
        u1s[t] = acc;
    } else if (t >= 64 && t < 86) {
        int a = t - 64;
        double acc = 0.0;
        const double* ra = T + a * 512;
        for (int d = 0; d < 512; ++d) acc += ra[d] * (double)Wg[512 + d];
        u2s[a] = acc;
    }
    __syncthreads();
    int w = t >> 6, lane = t & 63;
    const int* xb = x + w * 1024;
    const int* yb = y + w * 1024;
    double s = 0.0;
    for (int i = lane; i < 1024; i += 64) s += u1s[xb[i]] + u2s[yb[i]];
    for (int off = 32; off > 0; off >>= 1) s += __shfl_down(s, off);
    if (lane == 0) Aout[w] = s * (1.0 / 1024.0) + (double)bg[0];
}

// ---------------------------------------------------------------------------
// K3a: init V boundary (row 0 / col 0) + zero inter-block flags.
// ---------------------------------------------------------------------------
__global__ void k_vinit(float* __restrict__ Vbuf, int* __restrict__ gflag) {
    int b = blockIdx.x, t = threadIdx.x;
    float* Vb = Vbuf + (size_t)b * (1025 * 1025);
    Vb[t] = (t == 0) ? 0.0f : NEGV;                 // V[0][t]
    if (t == 0) Vb[1024] = NEGV;                    // V[0][1024]
    Vb[(size_t)(t + 1) * 1025] = NEGV;              // V[t+1][0]
    if (b == 0 && t < 64) gflag[t] = 0;
}

// ---------------------------------------------------------------------------
// K3b: split banded forward. NB blocks per batch (BW waves each, 1 wave/SIMD).
//      Block p owns rows 256p+1..256(p+1). Internal wave handoff via LDS
//      (16-col groups, WORKGROUP atomics — r10-verified). Inter-block handoff
//      via Vbuf global stores + AGENT-scope flag per 64-col chunk
//      (threadfence + release — r9-verified pattern). Per-cell float ops
//      verbatim -> bit-identical V.
// ---------------------------------------------------------------------------
__global__ __launch_bounds__(256) void k_fwds(const int* __restrict__ x,
                                              const int* __restrict__ y,
                                              const double* __restrict__ G,
                                              const double* __restrict__ Aarr,
                                              float* __restrict__ Vbuf,
                                              int* __restrict__ gflag) {
    __shared__ float Gs[484];
    __shared__ int ys_s[1024];
    __shared__ float topbuf[BW][1024];   // topbuf[w][c] = V[band_top + 64w][c+1]
    __shared__ int prog[BW];

    const int bid = blockIdx.x;
    const int b = bid & 7;               // batch (also XCD-affine)
    const int p = bid >> 3;              // row-block 0..NB-1
    const int tid = threadIdx.x;         // 0..255
    const int w = tid >> 6;              // wave within block
    const int t = tid & 63;              // lane = row within wave band
    const int grow = (p << 8) + tid;     // global (row-1): 256p + tid
    float* Vb = Vbuf + (size_t)b * (1025 * 1025);

    for (int q = tid; q < 484; q += 256) Gs[q] = (float)G[q];
    for (int q = tid; q < 1024; q += 256) ys_s[q] = y[(b << 10) + q];
    if (tid < BW) prog[tid] = 0;
    const int xs = x[(b << 10) + grow];
    __syncthreads();

    const float A = (float)Aarr[b];
    const float* Grow = Gs + xs * 22;
    float* vst = Vb + (size_t)(grow + 1) * 1025 + 1;      // vst[j-1] = V[grow+1][j]
    const float* tsrc = Vb + (size_t)(p << 8) * 1025;     // V[256p][*] (producer's bottom row)

    float vp = NEGV;                                      // V[row][j-1] carry
    float vdgc = (p == 0 && tid == 0) ? 0.0f : NEGV;      // V[row-1][j-1] carry seed
    float chunkv = NEGV;
    int cbase = 0;

    for (int s = 0; s < 1024 + 63; ++s) {
        // consumer blocks, wave 0: acquire + load producer chunk every 64 cols
        if (w == 0 && p > 0 && s < 1024 && (s & 63) == 0) {
            while (__hip_atomic_load(&gflag[(b << 2) + p - 1], __ATOMIC_ACQUIRE,
                                     __HIP_MEMORY_SCOPE_AGENT) < s + 64)
                __builtin_amdgcn_s_sleep(2);
            chunkv = tsrc[s + 1 + t];     // V[256p][s+1..s+64], bit-exact from global
            cbase = s;
        }
        // waves >0: internal LDS group-sync every 16 cols
        if (w > 0 && s < 1024 && (s & 15) == 0) {
            const int target = (s + 16 < 1024) ? s + 16 : 1024;
            while (__hip_atomic_load(&prog[w], __ATOMIC_ACQUIRE,
                                     __HIP_MEMORY_SCOPE_WORKGROUP) < target)
                __builtin_amdgcn_s_sleep(1);
        }
        float vu_l0;
        if (w == 0)
            vu_l0 = (p == 0) ? NEGV : __shfl(chunkv, s - cbase);
        else
            vu_l0 = topbuf[w][(s < 1024) ? s : 1023];
        const float ush = __shfl_up(vp, 1);   // lane t-1's v at col j
        const int j = s - t + 1;
        if (j >= 1 && j <= 1024) {
            float vu = (t == 0) ? vu_l0 : ush;
            float v = cellfwd(Grow[ys_s[j - 1]], vu, vdgc, vp, A);
            vst[j - 1] = v;                   // global store stays in flight
            if (t == 63) {
                if (w < BW - 1) {
                    topbuf[w + 1][j - 1] = v; // hand bottom row to next wave
                    if ((j & 15) == 0)
                        __hip_atomic_store(&prog[w + 1], j, __ATOMIC_RELEASE,
                                           __HIP_MEMORY_SCOPE_WORKGROUP);
                } else if (p < NB - 1) {
                    if ((j & 63) == 0) {      // publish chunk to next block
                        __threadfence();
                        __hip_atomic_store(&gflag[(b << 2) + p], j,
                                           __ATOMIC_RELEASE, __HIP_MEMORY_SCOPE_AGENT);
                    }
                }
            }
            vp = v; vdgc = vu;
        }
    }
}

// ---------------------------------------------------------------------------
// K4: weight kernel — recompute each cell's softmax weights (bit-identical
//     inputs from stored V), scatter into the packed-diagonal bundle layout.
// ---------------------------------------------------------------------------
__global__ __launch_bounds__(256) void k_wb(const double* __restrict__ Aarr,
                                            const float* __restrict__ Vbuf,
                                            float* __restrict__ bw) {
    int idx = blockIdx.x * 256 + threadIdx.x;
    int b = idx >> 20;
    int cell = idx & 1048575;
    int i = (cell >> 10) + 1;        // 1..1024
    int j = (cell & 1023) + 1;       // 1..1024
    const float* Vb = Vbuf + (size_t)b * (1025 * 1025);
    float vu  = Vb[(size_t)(i - 1) * 1025 + j];
    float vdg = Vb[(size_t)(i - 1) * 1025 + (j - 1)];
    float vl  = Vb[(size_t)i * 1025 + (j - 1)];
    float A = (float)Aarr[b];
    float t1 = vu + A;
    float t2 = vl + A;
    float di = t1 - vdg;
    float inner = (di > 0.f) ? (t1  + log1pf(expf(-di)))
                             : (vdg + log1pf(expf(di)));
    float dw = inner - t2;
    float outer = (dw > 0.f) ? (inner + log1pf(expf(-dw)))
                             : (t2    + log1pf(expf(dw)));
    float go1 = expf(inner - outer);
    float wlW = expf(t2 - outer);
    float wuW = go1 * expf(t1 - inner);
    float wdW = go1 * expf(vdg - inner);
    float* bbp = bw + (size_t)b * 3145728;

    if (i >= 2) {        // wu -> consumer (i-1, j)
        int rb = (i - 2) >> 4, q = (i - 2) & 15, cj = j - 1;
        int st, L, tlo; diag_geo(rb + cj, st, L, tlo);
        int f = 3 * q;
        bbp[(size_t)st * 48 + (size_t)(f >> 2) * 4 * L + ((rb - tlo) << 2) + (f & 3)] = wuW;
    }
    if (i >= 2 && j >= 2) {   // wd -> consumer (i-1, j-1)
        int rb = (i - 2) >> 4, q = (i - 2) & 15, cj = j - 2;
        int st, L, tlo; diag_geo(rb + cj, st, L, tlo);
        int f = 3 * q + 1;
        bbp[(size_t)st * 48 + (size_t)(f >> 2) * 4 * L + ((rb - tlo) << 2) + (f & 3)] = wdW;
    }
    if (j >= 2) {        // wl -> consumer (i, j-1)
        int rb = (i - 1) >> 4, q = (i - 1) & 15, cj = j - 2;
        int st, L, tlo; diag_geo(rb + cj, st, L, tlo);
        int f = 3 * q + 2;
        bbp[(size_t)st * 48 + (size_t)(f >> 2) * 4 * L + ((rb - tlo) << 2) + (f & 3)] = wlW;
    }
}

// ---------------------------------------------------------------------------
// K5: single-launch backward, packed-diagonal coalesced bundle reads.
//     (verbatim from the verified round-9 kernel; bit-identical E order)
// ---------------------------------------------------------------------------
__global__ __launch_bounds__(64) void k_bwd16(const float* __restrict__ bw,
                                              float* __restrict__ out) {
    const int t = threadIdx.x;
    const int b = blockIdx.x;
    const float* bb = bw + (size_t)b * 3145728;
    float* ob = out + ((size_t)b << 20);
    const int r0 = t << 4;              // (i-1) base = 16t

    float e[16];
    float4 cwv[12], pfv[12];
    #pragma unroll
    for (int q = 0; q < 16; ++q) e[q] = 0.f;

    {
        int st, L, tlo; diag_geo(t + 1023, st, L, tlo);
        const float* base = bb + (size_t)st * 48;
        #pragma unroll
        for (int k = 0; k < 12; ++k)
            cwv[k] = *(const float4*)(base + (size_t)k * 4 * L);
    }

    float sdb = 0.f;
    for (int s = 0; s < 1087; ++s) {
        float dn = __shfl_down(e[0], 1);    // lane t+1's top value at col cj
        const int d = 1086 - s;
        const int cj = d - t;               // this lane's column (j-1)
        if (cj >= 0 && cj < 1024) {
            {
                int st, L, tlo; diag_geo(d - 1, st, L, tlo);
                const int p = t - tlo;
                const float* base = bb + (size_t)st * 48 + ((size_t)p << 2);
                #pragma unroll
                for (int k = 0; k < 12; ++k)
                    pfv[k] = *(const float4*)(base + (size_t)k * 4 * L);
            }
            const float* F = (const float*)cwv;

            float old_b = e[15];
            float eu = (t == 63) ? 0.f : dn;
            float ed = (t == 63) ? 0.f : sdb;
            float v = eu * F[45] + ed * F[46] + old_b * F[47];
            if (t == 63 && cj == 1023) v = 1.0f;    // seed E[1024][1024] = 1
            e[15] = v;
            float new_b = v;
            #pragma unroll
            for (int q = 14; q >= 0; --q) {
                float oq = e[q];
                v = new_b * F[3 * q] + old_b * F[3 * q + 1] + oq * F[3 * q + 2];
                e[q] = v;
                new_b = v; old_b = oq;
            }
            #pragma unroll
            for (int k = 0; k < 4; ++k)
                *(float4*)&ob[(size_t)cj * 1024 + r0 + 4 * k] =
                    make_float4(e[4*k], e[4*k+1], e[4*k+2], e[4*k+3]);
            #pragma unroll
            for (int k = 0; k < 12; ++k) cwv[k] = pfv[k];
        }
        sdb = dn;
    }
}

// ---------------------------------------------------------------------------
// Fallback: round-2 monolithic forward+backward (used only if ws too small).
// ---------------------------------------------------------------------------
template <bool FAITHFUL>
__global__ __launch_bounds__(1024) void k_dp(const int* __restrict__ x,
                                             const int* __restrict__ y,
                                             const double* __restrict__ G,
                                             const double* __restrict__ Aarr,
                                             float2* __restrict__ wbuf,
                                             float* __restrict__ wdbuf,
                                             float* __restrict__ out) {
    __shared__ float Gs[484];
    __shared__ int xs[1024], ys[1024];
    __shared__ float D[3][1025];
    __shared__ float E[3][1026];

    const int b = blockIdx.x;
    const int t = threadIdx.x;
    const int i = t + 1;

    if (t < 484) Gs[t] = (float)G[t];
    xs[t] = x[(b << 10) + t];
    ys[t] = y[(b << 10) + t];
    D[0][t + 1] = NEGV;
    D[1][t + 1] = NEGV;
    E[0][t] = 0.f; E[1][t] = 0.f; E[2][t] = 0.f;
    if (t == 0) {
        D[0][0] = 0.0f;
        D[1][0] = NEGV;
        E[0][1024] = 0.f; E[0][1025] = 0.f;
        E[1][1024] = 0.f; E[1][1025] = 0.f;
        E[2][1024] = 0.f; E[2][1025] = 0.f;
    }
    __syncthreads();

    const float A = (float)Aarr[b];
    const float* Grow = Gs + xs[t] * 22;
    float2* wb = wbuf + ((size_t)b << 20);
    float*  wdb = wdbuf + ((size_t)b << 20);

    for (int k = 2; k <= 2048; ++k) {
        const int cur = k % 3, p1 = (k + 2) % 3, p2 = (k + 1) % 3;
        const int j = k - i;
        if (j >= 1 && j <= 1024) {
            float vu  = D[p1][i - 1];
            float vdg = D[p2][i - 1];
            float vl  = D[p1][i];
            float t1 = vu + A;
            float t2 = vl + A;
            float di = t1 - vdg;
            float inner = (di > 0.f) ? (t1  + log1pf(expf(-di)))
                                     : (vdg + log1pf(expf(di)));
            float dw = inner - t2;
            float outer = (dw > 0.f) ? (inner + log1pf(expf(-dw)))
                                     : (t2    + log1pf(expf(dw)));
            D[cur][i] = Grow[ys[j - 1]] + outer;
            float go1 = expf(inner - outer);
            float wlW = expf(t2 - outer);
            float wuW = go1 * expf(t1 - inner);
            size_t ci = ((size_t)t << 10) + (j - 1);
            wb[ci] = make_float2(wuW, wlW);
            if (FAITHFUL) wdb[ci] = go1 * expf(vdg - inner);
        }
        if (t == 0) D[cur][0] = NEGV;
        if (i == k && k <= 1024) D[cur][k] = NEGV;
        __syncthreads();
    }

    __syncthreads();

    float* ob = out + ((size_t)b << 20);

    for (int k = 2048; k >= 2; --k) {
        const int cur = k % 3, n1 = (k + 1) % 3, n2 = (k + 2) % 3;
        const int j = k - i;
        if (j >= 1 && j <= 1024) {
            float e;
            if (k == 2048) {
                e = 1.0f;
            } else {
                float Eu = E[n1][i + 1];
                float Ed = E[n2][i + 1];
                float El = E[n1][i];
                int iw = (i < 1024) ? i : 1023;
                int jw = (j < 1024) ? j : 1023;
                float2 w_up = wb[((size_t)iw << 10) + (j - 1)];
                float2 w_lf = wb[((size_t)(i - 1) << 10) + jw];
                float w_dd;
                if (FAITHFUL) {
                    w_dd = wdb[((size_t)iw << 10) + jw];
                } else {
                    float2 w_dg = wb[((size_t)iw << 10) + jw];
                    w_dd = 1.0f - w_dg.x - w_dg.y;
                }
                e = Eu * w_up.x + Ed * w_dd + El * w_lf.y;
            }
            E[cur][i] = e;
            ob[((size_t)(j - 1) << 10) + (i - 1)] = e;
        } else {
            E[cur][i] = 0.f;
        }
        __syncthreads();
    }
}

// ---------------------------------------------------------------------------
extern "C" void kernel_launch(void* const* d_in, const int* in_sizes, int n_in,
                              void* d_out, int out_size, void* d_ws, size_t ws_size,
                              hipStream_t stream) {
    const int*   x   = (const int*)d_in[0];
    const int*   y   = (const int*)d_in[1];
    const float* emb = (const float*)d_in[2];
    const float* W   = (const float*)d_in[3];
    const float* b   = (const float*)d_in[4];
    const float* Wg  = (const float*)d_in[5];
    const float* bg  = (const float*)d_in[6];
    float* out = (float*)d_out;

    char* ws = (char*)d_ws;
    double* T    = (double*)(ws + 0);                       // 90112 B
    double* G    = (double*)(ws + 90112);                   // 3872 B
    double* Aarr = (double*)(ws + 94336);                   // 64 B
    float*  bund = (float*)(ws + 131072);                   // 96 MiB (packed diagonals)
    float2* wbuf = (float2*)(ws + 131072);                  // (fallback layout)
    float*  wdbuf = (float*)(ws + 131072 + ((size_t)64 << 20));
    float*  Vbuf = (float*)(ws + 131072 + ((size_t)96 << 20));   // 33.6 MB
    int*    gflag = (int*)(ws + 131072 + ((size_t)96 << 20) + (size_t)8 * 1025 * 1025 * 4);

    k_embed<<<44, 256, 0, stream>>>(emb, W, b, T);
    k_gau<<<1, 512, 0, stream>>>(T, x, y, Wg, bg, G, Aarr);

    const size_t need_old = 131072 + ((size_t)96 << 20);
    const size_t need_new = need_old + (size_t)8 * 1025 * 1025 * 4 + 4096;

    if (ws_size >= need_new) {
        k_vinit<<<8, 1024, 0, stream>>>(Vbuf, gflag);
        k_fwds<<<8 * NB, 256, 0, stream>>>(x, y, G, Aarr, Vbuf, gflag);
        k_wb<<<8 * 1024 * 1024 / 256, 256, 0, stream>>>(Aarr, Vbuf, bund);
        k_bwd16<<<8, 64, 0, stream>>>(bund, out);
    } else if (ws_size >= need_old) {
        k_dp<true><<<8, 1024, 0, stream>>>(x, y, G, Aarr, wbuf, wdbuf, out);
    } else {
        k_dp<false><<<8, 1024, 0, stream>>>(x, y, G, Aarr, wbuf, wdbuf, out);
    }
}